// Round 1
// baseline (296.230 us; speedup 1.0000x reference)
//
#include <hip/hip_runtime.h>

#define A_ALLELES 4096
#define CCH 12     // input channels
#define LW 32      // read window length
#define DH 32      // hidden dim
#define RDF (CCH * LW)          // floats per read = 384
#define CHF (2 * RDF)           // floats per 2-read chunk = 768

typedef __attribute__((ext_vector_type(8)))  short bf16x8;   // 4 VGPRs
typedef __attribute__((ext_vector_type(16))) float f32x16;   // 16 VGPRs

// pack two fp32 -> two bf16 (round-half-up; used for hoisted W and rare tail)
__device__ inline unsigned pk2(float fa, float fb) {
    const unsigned a = __float_as_uint(fa), b = __float_as_uint(fb);
    return ((a + 0x8000u) >> 16) | ((b + 0x8000u) & 0xffff0000u);
}

// hardware packed convert (RNE), 1 instr per bf16 pair
__device__ inline unsigned cvtpk(float lo, float hi) {
    unsigned r;
    asm("v_cvt_pk_bf16_f32 %0, %1, %2" : "=v"(r) : "v"(lo), "v"(hi));
    return r;
}

// direct global->LDS, 16B per lane; LDS dest = wave-uniform base + lane*16
#define GLD16(gp, lp) __builtin_amdgcn_global_load_lds(                   \
        (const __attribute__((address_space(1))) void*)(gp),              \
        (__attribute__((address_space(3))) void*)(lp), 16, 0, 0)

// ---------------------------------------------------------------------------
// Kernel 1: exclusive prefix-sum of the two per-allele read-count arrays.
// ---------------------------------------------------------------------------
__global__ __launch_bounds__(256) void scan_kernel(
    const int* __restrict__ c0, const int* __restrict__ c1,
    int* __restrict__ o0, int* __restrict__ o1)
{
    const int* c = (blockIdx.x == 0) ? c0 : c1;
    int*       o = (blockIdx.x == 0) ? o0 : o1;

    __shared__ int part[256];
    const int tid  = threadIdx.x;
    const int base = tid * 16;

    int loc[16];
    int s = 0;
#pragma unroll
    for (int i = 0; i < 16; ++i) { loc[i] = c[base + i]; s += loc[i]; }
    part[tid] = s;
    __syncthreads();

    for (int st = 1; st < 256; st <<= 1) {
        int v = (tid >= st) ? part[tid - st] : 0;
        __syncthreads();
        part[tid] += v;
        __syncthreads();
    }

    int excl = (tid == 0) ? 0 : part[tid - 1];
#pragma unroll
    for (int i = 0; i < 16; ++i) { o[base + i] = excl; excl += loc[i]; }
}

// ---------------------------------------------------------------------------
// Kernel 2: one wave per (allele, src). Reads staged 2-at-a-time into LDS via
// global_load_lds dwordx4 (3 x 1KB per chunk, double-buffered, counted vmcnt:
// steady state keeps 6 loads in flight, waits to 3 - never drains to 0).
// Fragment gather from LDS: 8 x ds_read_b32/read, lane-stride 4B -> 2 lanes
// per bank = conflict-free. MFMA mapping identical to the verified scalar
// version: A = W (A[m=d=lane&31][k=(lane>>5)*8+j], zeros at k>=12), B from
// LDS chunk: lane(h=lane>>5,l=lane&31) reads c=h*8+{0..3} and (h?8..11:4..7)
// (h=1 j>=4 dead but finite). Bias via C operand. relu+acc in 16 regs;
// epilogue shfl-reduce over l, fold 1/(32*depth) + W2 head, 2 atomics/(a,src).
// ---------------------------------------------------------------------------
__global__ __launch_bounds__(256, 4) void main_kernel(
    const float* __restrict__ t0, const float* __restrict__ t1,
    const float* __restrict__ W0, const float* __restrict__ b0,
    const float* __restrict__ W1, const float* __restrict__ b1,
    const float* __restrict__ W2, const float* __restrict__ b2,
    const int*  __restrict__ cnt0, const int* __restrict__ cnt1,
    const float* __restrict__ dm0, const float* __restrict__ dm1,
    const int*  __restrict__ offs0, const int* __restrict__ offs1,
    float* __restrict__ out)
{
    __shared__ float sW2[2 * 2 * DH];    // [NOUT][2D] flat = 128
    __shared__ float sB2[2];
    __shared__ float stg[4][2][CHF];     // 4 waves x 2 bufs x 768 f = 24576 B

    const int tid = threadIdx.x;
    if (tid < 2 * 2 * DH) sW2[tid] = W2[tid];
    if (tid < 2) sB2[tid] = b2[tid];
    __syncthreads();                     // once; main loop is barrier-free

    const int w    = tid >> 6;
    const int lane = tid & 63;
    const int src  = blockIdx.x >> 10;                  // block-uniform
    const int a    = ((blockIdx.x & 1023) << 2) | w;    // 0..4095

    const float* __restrict__ tens = src ? t1 : t0;
    const int*   __restrict__ cnt  = src ? cnt1 : cnt0;
    const int*   __restrict__ offs = src ? offs1 : offs0;
    const float* __restrict__ dm   = src ? dm1 : dm0;
    const float* __restrict__ gW   = src ? W1 : W0;
    const float* __restrict__ gB   = src ? b1 : b0;

    const int l = lane & 31;             // B column / D column
    const int h = lane >> 5;             // k-half selector

    // ---- hoisted: A fragment from W: A[m=d=l][k=h*8+j], zero k>=12 -------
    union { bf16x8 v; unsigned u[4]; } Af;
#pragma unroll
    for (int p = 0; p < 4; ++p) {
        const int c0 = h * 8 + 2 * p, c1 = c0 + 1;
        const float f0 = (c0 < CCH) ? gW[l * CCH + c0] : 0.f;
        const float f1 = (c1 < CCH) ? gW[l * CCH + c1] : 0.f;
        Af.u[p] = pk2(f0, f1);
    }
    // ---- hoisted: bias via C operand: C[row=d][col] = b[d] ---------------
    f32x16 cb;
#pragma unroll
    for (int reg = 0; reg < 16; ++reg)
        cb[reg] = gB[(reg & 3) + 8 * (reg >> 2) + 4 * h];

    const int n     = cnt[a];
    const int start = offs[a];
    const float* rb = tens + (size_t)start * RDF;

    float acc[16];
#pragma unroll
    for (int r = 0; r < 16; ++r) acc[r] = 0.f;

    const int base0 = h * 256 + l;       // float idx of (c=8h, l) in a read

    const int nch = (n & ~1) >> 1;       // 2-read chunks (n is 16/24)

    if (nch > 0) {
        // prologue: stage chunk 0 (+1) -> 3 (6) loads outstanding
        {
            const float* g = rb + (size_t)lane * 4;
            GLD16(g,       &stg[w][0][0]);
            GLD16(g + 256, &stg[w][0][256]);
            GLD16(g + 512, &stg[w][0][512]);
        }
        if (nch > 1) {
            const float* g = rb + CHF + (size_t)lane * 4;
            GLD16(g,       &stg[w][1][0]);
            GLD16(g + 256, &stg[w][1][256]);
            GLD16(g + 512, &stg[w][1][512]);
        }
        for (int ch = 0; ch < nch; ++ch) {
            const int cur = ch & 1;
            // chunk ch landed when <=3 (next chunk's loads) remain in flight
            if (ch + 1 < nch) { asm volatile("s_waitcnt vmcnt(3)" ::: "memory"); }
            else              { asm volatile("s_waitcnt vmcnt(0)" ::: "memory"); }
#pragma unroll
            for (int q = 0; q < 2; ++q) {
                const int off  = q * RDF + base0;          // c = 8h + j
                const int off2 = off + (h ? 0 : 128);      // c = 4..7 / 8..11
                const float v0 = stg[w][cur][off];
                const float v1 = stg[w][cur][off + 32];
                const float v2 = stg[w][cur][off + 64];
                const float v3 = stg[w][cur][off + 96];
                const float v4 = stg[w][cur][off2];
                const float v5 = stg[w][cur][off2 + 32];
                const float v6 = stg[w][cur][off2 + 64];
                const float v7 = stg[w][cur][off2 + 96];
                union { bf16x8 v; unsigned u[4]; } Bf;
                Bf.u[0] = cvtpk(v0, v1); Bf.u[1] = cvtpk(v2, v3);
                Bf.u[2] = cvtpk(v4, v5); Bf.u[3] = cvtpk(v6, v7);
                const f32x16 D = __builtin_amdgcn_mfma_f32_32x32x16_bf16(
                    Af.v, Bf.v, cb, 0, 0, 0);
#pragma unroll
                for (int r = 0; r < 16; ++r) acc[r] += fmaxf(D[r], 0.f);
            }
            if (ch + 2 < nch) {
                // drain ds_reads of buf[cur] before its overwrite lands
                asm volatile("s_waitcnt lgkmcnt(0)" ::: "memory");
                const float* g = rb + (size_t)(ch + 2) * CHF + (size_t)lane * 4;
                GLD16(g,       &stg[w][cur][0]);
                GLD16(g + 256, &stg[w][cur][256]);
                GLD16(g + 512, &stg[w][cur][512]);
            }
        }
    }

    if (n & 1) {                         // safety tail (counts are 16/24)
        const float* qLo = rb + (size_t)(n - 1) * RDF + l + h * 256;
        const float* qHi = rb + (size_t)(n - 1) * RDF + l + (h ? 256 : 128);
        const float u0 = qLo[0],  u1 = qLo[32], u2 = qLo[64], u3 = qLo[96];
        const float u4 = qHi[0],  u5 = qHi[32], u6 = qHi[64], u7 = qHi[96];
        union { bf16x8 v; unsigned u[4]; } Bf;
        Bf.u[0] = pk2(u0, u1); Bf.u[1] = pk2(u2, u3);
        Bf.u[2] = pk2(u4, u5); Bf.u[3] = pk2(u6, u7);
        const f32x16 D = __builtin_amdgcn_mfma_f32_32x32x16_bf16(
            Af.v, Bf.v, cb, 0, 0, 0);
#pragma unroll
        for (int r = 0; r < 16; ++r) acc[r] += fmaxf(D[r], 0.f);
    }

    // reduce over l (cols): masks 1..16 stay within each 32-lane half
#pragma unroll
    for (int r = 0; r < 16; ++r) {
#pragma unroll
        for (int mm = 1; mm < 32; mm <<= 1)
            acc[r] += __shfl_xor(acc[r], mm, 64);
    }

    const float scale = 1.f / (32.f * dm[a]);
    float c0s = 0.f, c1s = 0.f;
#pragma unroll
    for (int r = 0; r < 16; ++r) {
        const int d = (r & 3) + 8 * (r >> 2) + 4 * h;
        const float pv = acc[r] * scale;     // pooled[a, src*32 + d]
        c0s = fmaf(pv, sW2[0 * 2 * DH + src * DH + d], c0s);
        c1s = fmaf(pv, sW2[1 * 2 * DH + src * DH + d], c1s);
    }
    // combine the two h-halves (each held 16 of the 32 d's)
    c0s += __shfl_xor(c0s, 32, 64);
    c1s += __shfl_xor(c1s, 32, 64);

    if (lane == 0) {
        if (src == 0) { c0s += sB2[0]; c1s += sB2[1]; }
        atomicAdd(&out[a * 2 + 0], c0s);
        atomicAdd(&out[a * 2 + 1], c1s);
    }
}

extern "C" void kernel_launch(void* const* d_in, const int* in_sizes, int n_in,
                              void* d_out, int out_size, void* d_ws, size_t ws_size,
                              hipStream_t stream) {
    const float* t0  = (const float*)d_in[0];
    const float* t1  = (const float*)d_in[1];
    const float* W0  = (const float*)d_in[2];
    const float* b0  = (const float*)d_in[3];
    const float* W1  = (const float*)d_in[4];
    const float* b1  = (const float*)d_in[5];
    const float* W2  = (const float*)d_in[6];
    const float* b2  = (const float*)d_in[7];
    const int*  cnt0 = (const int*)d_in[8];
    const int*  cnt1 = (const int*)d_in[9];
    // d_in[10] = numAllelesPerSite (unused by the reference math)
    const float* dm0 = (const float*)d_in[11];
    const float* dm1 = (const float*)d_in[12];

    int* offs0 = (int*)d_ws;
    int* offs1 = offs0 + A_ALLELES;

    hipMemsetAsync(d_out, 0, (size_t)out_size * sizeof(float), stream);
    scan_kernel<<<2, 256, 0, stream>>>(cnt0, cnt1, offs0, offs1);

    main_kernel<<<2048, 256, 0, stream>>>(
        t0, t1, W0, b0, W1, b1, W2, b2,
        cnt0, cnt1, dm0, dm1, offs0, offs1, (float*)d_out);
}